// Round 20
// baseline (146.976 us; speedup 1.0000x reference)
//
#include <hip/hip_runtime.h>

typedef short bf16x8 __attribute__((ext_vector_type(8)));
typedef float f32x4 __attribute__((ext_vector_type(4)));
typedef unsigned short ushort8v __attribute__((ext_vector_type(8)));
typedef unsigned short ushort4v __attribute__((ext_vector_type(4)));

__device__ __forceinline__ unsigned short f2bf(float f) {
  unsigned u = __float_as_uint(f);
  u += 0x7FFF + ((u >> 16) & 1);   // round-to-nearest-even
  return (unsigned short)(u >> 16);
}

// ---------------------------------------------------------------------------
// Kernel 0: weights -> WbT [640][512] bf16 (Wq pre-scaled by log2e).
// ---------------------------------------------------------------------------
__global__ void wt_prep(const float* __restrict__ Wq, const float* __restrict__ Wk,
                        const float* __restrict__ Wv, unsigned short* __restrict__ WbT) {
  int idx = blockIdx.x * 256 + threadIdx.x;   // 640*512 = 327680 total
  int o = idx >> 9, c = idx & 511;
  float v;
  if (o < 64)       v = Wq[c * 64 + o] * 1.44269504f;
  else if (o < 128) v = Wk[c * 64 + (o - 64)];
  else              v = Wv[(size_t)c * 512 + (o - 128)];
  WbT[idx] = f2bf(v);
}

// ---------------------------------------------------------------------------
// Kernel 1: projection GEMM  [16384,512] x [512,640] -> q,k row-major bf16 and
// v transposed vT[b][512][4096] bf16. (validated rounds 3-19, unchanged)
// ---------------------------------------------------------------------------
__global__ __launch_bounds__(256, 2) void proj_gemm(
    const float* __restrict__ x, const unsigned short* __restrict__ WbT,
    unsigned short* __restrict__ q, unsigned short* __restrict__ k,
    unsigned short* __restrict__ vT) {
  __shared__ unsigned short As[128][72];   // 64 + 8 pad
  const int tid = threadIdx.x;
  const int wid = tid >> 6, lane = tid & 63;
  const int l15 = lane & 15, l4 = lane >> 4;
  const int mtile = blockIdx.x, ntile = blockIdx.y;
  const int rbase = mtile * 128;
  const int wr = (wid >> 1) * 64, wc = (wid & 1) * 64;

  f32x4 acc[4][4] = {};

  const int arow = tid >> 2;         // 0..63
  const int akof = (tid & 3) * 16;   // 0,16,32,48

  for (int kb = 0; kb < 512; kb += 64) {
    f32x4 t0[2][4];
#pragma unroll
    for (int pass = 0; pass < 2; ++pass) {
      const float* src = x + (size_t)(rbase + pass * 64 + arow) * 512 + kb + akof;
#pragma unroll
      for (int i = 0; i < 4; ++i) t0[pass][i] = *(const f32x4*)(src + i * 4);
    }
    __syncthreads();
#pragma unroll
    for (int pass = 0; pass < 2; ++pass) {
      unsigned short tmp[16];
#pragma unroll
      for (int i = 0; i < 4; ++i)
#pragma unroll
        for (int j = 0; j < 4; ++j) tmp[i * 4 + j] = f2bf(t0[pass][i][j]);
      unsigned short* dst = &As[pass * 64 + arow][akof];
      *(ushort8v*)(dst)     = *(ushort8v*)(tmp);
      *(ushort8v*)(dst + 8) = *(ushort8v*)(tmp + 8);
    }
    __syncthreads();

    bf16x8 af[4][2], bfr[4][2];
#pragma unroll
    for (int mr = 0; mr < 4; ++mr)
#pragma unroll
      for (int ks = 0; ks < 2; ++ks)
        af[mr][ks] = *(const bf16x8*)&As[wr + mr * 16 + l15][ks * 32 + l4 * 8];
#pragma unroll
    for (int nc = 0; nc < 4; ++nc)
#pragma unroll
      for (int ks = 0; ks < 2; ++ks) {
        int col = ntile * 128 + wc + nc * 16 + l15;
        bfr[nc][ks] = *(const bf16x8*)(WbT + (size_t)col * 512 + kb + ks * 32 + l4 * 8);
      }
#pragma unroll
    for (int ks = 0; ks < 2; ++ks)
#pragma unroll
      for (int mr = 0; mr < 4; ++mr)
#pragma unroll
        for (int nc = 0; nc < 4; ++nc)
          acc[mr][nc] = __builtin_amdgcn_mfma_f32_16x16x32_bf16(af[mr][ks], bfr[nc][ks],
                                                                acc[mr][nc], 0, 0, 0);
  }

  if (ntile == 0) {
    unsigned short* dst = (wid & 1) ? k : q;
#pragma unroll
    for (int mr = 0; mr < 4; ++mr)
#pragma unroll
      for (int nc = 0; nc < 4; ++nc)
#pragma unroll
        for (int r = 0; r < 4; ++r) {
          int grow = rbase + wr + mr * 16 + l4 * 4 + r;
          int col = nc * 16 + l15;
          dst[(size_t)grow * 64 + col] = f2bf(acc[mr][nc][r]);
        }
  } else {
#pragma unroll
    for (int mr = 0; mr < 4; ++mr)
#pragma unroll
      for (int nc = 0; nc < 4; ++nc) {
        int col = ntile * 128 + wc + nc * 16 + l15 - 128;   // 0..511
        int grow = rbase + wr + mr * 16 + l4 * 4;
        int b = grow >> 12, m = grow & 4095;
        ushort4v pk;
#pragma unroll
        for (int r = 0; r < 4; ++r) pk[r] = f2bf(acc[mr][nc][r]);
        *(ushort4v*)(vT + ((size_t)b * 512 + col) * 4096 + m) = pk;
      }
  }
}

// ---------------------------------------------------------------------------
// Kernel 2 (v18): fused sigmoid-attention = v16 with the P-pipeline shifted
// by one chunk: sigmoid(it+1)+Pwrite moved AFTER PV(it), so one barrier
// region contains S(it+1) [reg MFMA] + PV(it) [LDS+MFMA] + sigmoid [VALU] +
// V/K loads -> waves co-issue all three pipes. P's write->barrier->read
// pattern is now ISOMORPHIC to V's (proven v5/v12/v16): write buf^1 after
// region's reads, read after next barrier. No swizzle, no triple-buffer.
// Grid (32 rt, 2 ct, 4 b) = 256 blocks x 512 threads (8 waves), 1 block/CU.
// Fragment-major layouts (v16-proven). LDS 96 KB.
// ---------------------------------------------------------------------------
__global__ __launch_bounds__(512, 1) void attn_fused(
    const float* __restrict__ x, const unsigned short* __restrict__ q,
    const unsigned short* __restrict__ k, const unsigned short* __restrict__ vT,
    const float* __restrict__ gamma, float* __restrict__ out) {
  __shared__ unsigned short Vs[2][16][8][16][8];   // 64 KB [buf][cf][s][l15][e]
  __shared__ unsigned short Ps[2][8][8][16][8];    // 32 KB [buf][f][s][l15][e]
  const int tid = threadIdx.x, w = tid >> 6, lane = tid & 63;
  const int l15 = lane & 15, l4 = lane >> 4;
  const int rhalf = w >> 2;      // S: q-row half
  const int mt = w & 3;          // S: m-tile
  const int pvt = w >> 1;        // PV: col-group (0..3)
  const int ms = w & 1;          // PV: m-half (0..1)
  const int rt = blockIdx.x, ct = blockIdx.y, b = blockIdx.z;
  const int rbase = rt * 128, cbase = ct * 256;
  const unsigned short* qb = q + (size_t)b * 4096 * 64;
  const unsigned short* kp = k + (size_t)b * 4096 * 64;
  const unsigned short* vb = vT + (size_t)b * 512 * 4096;
  const float gv = gamma[0];
  const int vst_c = tid >> 1, vhalf = tid & 1;   // V staging: 64 B/thread

  // q fragments, register-resident
  bf16x8 qf[4][2];
#pragma unroll
  for (int rf = 0; rf < 4; ++rf)
#pragma unroll
    for (int ks = 0; ks < 2; ++ks)
      qf[rf][ks] = *(const bf16x8*)(qb +
          (size_t)(rbase + rhalf * 64 + rf * 16 + l15) * 64 + ks * 32 + l4 * 8);

  // ---- prologue: V(0)->Vs[0]; S(0)+sigmoid+Pwrite->Ps[0]; K(1)->kfc ----
  {
    bf16x8 vv[4];
#pragma unroll
    for (int i = 0; i < 4; ++i)
      vv[i] = *(const bf16x8*)(vb + (size_t)(cbase + vst_c) * 4096 + vhalf * 32 + i * 8);
#pragma unroll
    for (int i = 0; i < 4; ++i)
      *(bf16x8*)&Vs[0][vst_c >> 4][vhalf * 4 + i][vst_c & 15][0] = vv[i];

    bf16x8 k0[2];
#pragma unroll
    for (int ks = 0; ks < 2; ++ks)
      k0[ks] = *(const bf16x8*)(kp + (size_t)(mt * 16 + l15) * 64 + ks * 32 + l4 * 8);
    f32x4 s0[4] = {};
#pragma unroll
    for (int ks = 0; ks < 2; ++ks)
#pragma unroll
      for (int rf = 0; rf < 4; ++rf)
        s0[rf] = __builtin_amdgcn_mfma_f32_16x16x32_bf16(k0[ks], qf[rf][ks], s0[rf], 0, 0, 0);
#pragma unroll
    for (int rf = 0; rf < 4; ++rf) {
      ushort4v pk;
#pragma unroll
      for (int r = 0; r < 4; ++r)
        pk[r] = f2bf(__builtin_amdgcn_rcpf(1.0f + __builtin_amdgcn_exp2f(-s0[rf][r])));
      *(ushort4v*)&Ps[0][rhalf * 4 + rf][mt * 2 + (l4 >> 1)][l15][(l4 & 1) * 4] = pk;
    }
  }
  bf16x8 kfc[2];
#pragma unroll
  for (int ks = 0; ks < 2; ++ks)
    kfc[ks] = *(const bf16x8*)(kp + (size_t)(64 + mt * 16 + l15) * 64 + ks * 32 + l4 * 8);
  __syncthreads();

  f32x4 oacc[8][4] = {};   // 128 rows x 64 cols partial (m-half ms)

  for (int it = 0; it < 64; ++it) {
    const bool pf = (it < 63);
    const int p = it & 1;
    const int kn = (it + 2 < 64) ? (it + 2) : 63;   // K prefetch index (clamped)
    bf16x8 kfn[2], vv[4];
    f32x4 sacc[4] = {};

    if (pf) {
      // ---- issue V(it+1) and K(it+2) loads (consumed at region bottom) ----
#pragma unroll
      for (int i = 0; i < 4; ++i)
        vv[i] = *(const bf16x8*)(vb + (size_t)(cbase + vst_c) * 4096 +
                                 (it + 1) * 64 + vhalf * 32 + i * 8);
#pragma unroll
      for (int ks = 0; ks < 2; ++ks)
        kfn[ks] = *(const bf16x8*)(kp + (size_t)(kn * 64 + mt * 16 + l15) * 64 +
                                   ks * 32 + l4 * 8);
      // ---- S(it+1): pure-register MFMA (K(it+1) in kfc, Q in qf) ----
#pragma unroll
      for (int ks = 0; ks < 2; ++ks)
#pragma unroll
        for (int rf = 0; rf < 4; ++rf)
          sacc[rf] = __builtin_amdgcn_mfma_f32_16x16x32_bf16(kfc[ks], qf[rf][ks],
                                                             sacc[rf], 0, 0, 0);
    }

    // ---- PV(it): tile 128 rows x 64 cols (pvt), m-slice ms*32..+32 ----
    __builtin_amdgcn_s_setprio(1);
    {
      bf16x8 af[8], bfr[4];
#pragma unroll
      for (int mr = 0; mr < 8; ++mr)
        af[mr] = *(const bf16x8*)&Ps[p][mr][ms * 4 + l4][l15][0];
#pragma unroll
      for (int nc = 0; nc < 4; ++nc)
        bfr[nc] = *(const bf16x8*)&Vs[p][pvt * 4 + nc][ms * 4 + l4][l15][0];
#pragma unroll
      for (int mr = 0; mr < 8; ++mr)
#pragma unroll
        for (int nc = 0; nc < 4; ++nc)
          oacc[mr][nc] = __builtin_amdgcn_mfma_f32_16x16x32_bf16(af[mr], bfr[nc],
                                                                 oacc[mr][nc], 0, 0, 0);
    }
    __builtin_amdgcn_s_setprio(0);

    if (pf) {
      // ---- sigmoid(it+1) + Pwrite -> Ps[p^1] (isomorphic to V pattern) ----
#pragma unroll
      for (int rf = 0; rf < 4; ++rf) {
        ushort4v pk;
#pragma unroll
        for (int r = 0; r < 4; ++r)
          pk[r] = f2bf(__builtin_amdgcn_rcpf(1.0f + __builtin_amdgcn_exp2f(-sacc[rf][r])));
        *(ushort4v*)&Ps[p ^ 1][rhalf * 4 + rf][mt * 2 + (l4 >> 1)][l15][(l4 & 1) * 4] = pk;
      }
      // ---- Vwrite(it+1) -> Vs[p^1]; rotate K frags ----
#pragma unroll
      for (int i = 0; i < 4; ++i)
        *(bf16x8*)&Vs[p ^ 1][vst_c >> 4][vhalf * 4 + i][vst_c & 15][0] = vv[i];
      kfc[0] = kfn[0]; kfc[1] = kfn[1];
    }
    __syncthreads();   // the ONLY barrier per chunk
  }

  // ---- epilogue: pair-reduce (ms=1 -> ms=0) via LDS, then gamma*O + x ----
  float* red = (float*)&Vs[0][0][0][0][0];   // 4 tiles x 64 rows x 64 cols f32 = 64 KB
  __syncthreads();   // chunk loop done; safe to reuse Vs
#pragma unroll
  for (int h = 0; h < 2; ++h) {
    if (ms == 1) {
#pragma unroll
      for (int m4 = 0; m4 < 4; ++m4)
#pragma unroll
        for (int nc = 0; nc < 4; ++nc)
#pragma unroll
          for (int r = 0; r < 4; ++r)
            red[(pvt * 64 + m4 * 16 + l4 * 4 + r) * 64 + nc * 16 + l15] =
                oacc[h * 4 + m4][nc][r];
    }
    __syncthreads();
    if (ms == 0) {
#pragma unroll
      for (int m4 = 0; m4 < 4; ++m4)
#pragma unroll
        for (int nc = 0; nc < 4; ++nc)
#pragma unroll
          for (int r = 0; r < 4; ++r) {
            int mr = h * 4 + m4;
            float sum = oacc[mr][nc][r] +
                red[(pvt * 64 + m4 * 16 + l4 * 4 + r) * 64 + nc * 16 + l15];
            int grow = rbase + mr * 16 + l4 * 4 + r;
            int col = cbase + pvt * 64 + nc * 16 + l15;
            size_t idx = ((size_t)b * 4096 + grow) * 512 + col;
            out[idx] = gv * sum + x[idx];
          }
    }
    __syncthreads();
  }
}

extern "C" void kernel_launch(void* const* d_in, const int* in_sizes, int n_in,
                              void* d_out, int out_size, void* d_ws, size_t ws_size,
                              hipStream_t stream) {
  const float* x     = (const float*)d_in[0];
  const float* Wq    = (const float*)d_in[1];
  const float* Wk    = (const float*)d_in[2];
  const float* Wv    = (const float*)d_in[3];
  const float* gamma = (const float*)d_in[4];
  float* out = (float*)d_out;

  char* ws = (char*)d_ws;
  unsigned short* qbuf = (unsigned short*)(ws);                       // 2 MB
  unsigned short* kbuf = (unsigned short*)(ws + (2ull << 20));        // 2 MB
  unsigned short* vT   = (unsigned short*)(ws + (4ull << 20));        // 16 MB
  unsigned short* WbT  = (unsigned short*)(ws + (20ull << 20));       // 640 KB

  hipLaunchKernelGGL(wt_prep, dim3(1280), dim3(256), 0, stream, Wq, Wk, Wv, WbT);
  hipLaunchKernelGGL(proj_gemm, dim3(128, 5), dim3(256), 0, stream, x, WbT, qbuf, kbuf, vT);
  hipLaunchKernelGGL(attn_fused, dim3(32, 2, 4), dim3(512), 0, stream,
                     x, qbuf, kbuf, vT, gamma, out);
}

// Round 21
// 142.269 us; speedup vs baseline: 1.0331x; 1.0331x over previous
//
#include <hip/hip_runtime.h>

typedef short bf16x8 __attribute__((ext_vector_type(8)));
typedef float f32x4 __attribute__((ext_vector_type(4)));
typedef unsigned short ushort8v __attribute__((ext_vector_type(8)));
typedef unsigned short ushort4v __attribute__((ext_vector_type(4)));

__device__ __forceinline__ unsigned short f2bf(float f) {
  unsigned u = __float_as_uint(f);
  u += 0x7FFF + ((u >> 16) & 1);   // round-to-nearest-even
  return (unsigned short)(u >> 16);
}

// ---------------------------------------------------------------------------
// Kernel 0: weights -> WbT [640][512] bf16 (Wq pre-scaled by log2e).
// ---------------------------------------------------------------------------
__global__ void wt_prep(const float* __restrict__ Wq, const float* __restrict__ Wk,
                        const float* __restrict__ Wv, unsigned short* __restrict__ WbT) {
  int idx = blockIdx.x * 256 + threadIdx.x;   // 640*512 = 327680 total
  int o = idx >> 9, c = idx & 511;
  float v;
  if (o < 64)       v = Wq[c * 64 + o] * 1.44269504f;
  else if (o < 128) v = Wk[c * 64 + (o - 64)];
  else              v = Wv[(size_t)c * 512 + (o - 128)];
  WbT[idx] = f2bf(v);
}

// ---------------------------------------------------------------------------
// Kernel 1: projection GEMM  [16384,512] x [512,640] -> q,k row-major bf16 and
// v transposed vT[b][512][4096] bf16. (validated rounds 3-20, unchanged)
// ---------------------------------------------------------------------------
__global__ __launch_bounds__(256, 2) void proj_gemm(
    const float* __restrict__ x, const unsigned short* __restrict__ WbT,
    unsigned short* __restrict__ q, unsigned short* __restrict__ k,
    unsigned short* __restrict__ vT) {
  __shared__ unsigned short As[128][72];   // 64 + 8 pad
  const int tid = threadIdx.x;
  const int wid = tid >> 6, lane = tid & 63;
  const int l15 = lane & 15, l4 = lane >> 4;
  const int mtile = blockIdx.x, ntile = blockIdx.y;
  const int rbase = mtile * 128;
  const int wr = (wid >> 1) * 64, wc = (wid & 1) * 64;

  f32x4 acc[4][4] = {};

  const int arow = tid >> 2;         // 0..63
  const int akof = (tid & 3) * 16;   // 0,16,32,48

  for (int kb = 0; kb < 512; kb += 64) {
    f32x4 t0[2][4];
#pragma unroll
    for (int pass = 0; pass < 2; ++pass) {
      const float* src = x + (size_t)(rbase + pass * 64 + arow) * 512 + kb + akof;
#pragma unroll
      for (int i = 0; i < 4; ++i) t0[pass][i] = *(const f32x4*)(src + i * 4);
    }
    __syncthreads();
#pragma unroll
    for (int pass = 0; pass < 2; ++pass) {
      unsigned short tmp[16];
#pragma unroll
      for (int i = 0; i < 4; ++i)
#pragma unroll
        for (int j = 0; j < 4; ++j) tmp[i * 4 + j] = f2bf(t0[pass][i][j]);
      unsigned short* dst = &As[pass * 64 + arow][akof];
      *(ushort8v*)(dst)     = *(ushort8v*)(tmp);
      *(ushort8v*)(dst + 8) = *(ushort8v*)(tmp + 8);
    }
    __syncthreads();

    bf16x8 af[4][2], bfr[4][2];
#pragma unroll
    for (int mr = 0; mr < 4; ++mr)
#pragma unroll
      for (int ks = 0; ks < 2; ++ks)
        af[mr][ks] = *(const bf16x8*)&As[wr + mr * 16 + l15][ks * 32 + l4 * 8];
#pragma unroll
    for (int nc = 0; nc < 4; ++nc)
#pragma unroll
      for (int ks = 0; ks < 2; ++ks) {
        int col = ntile * 128 + wc + nc * 16 + l15;
        bfr[nc][ks] = *(const bf16x8*)(WbT + (size_t)col * 512 + kb + ks * 32 + l4 * 8);
      }
#pragma unroll
    for (int ks = 0; ks < 2; ++ks)
#pragma unroll
      for (int mr = 0; mr < 4; ++mr)
#pragma unroll
        for (int nc = 0; nc < 4; ++nc)
          acc[mr][nc] = __builtin_amdgcn_mfma_f32_16x16x32_bf16(af[mr][ks], bfr[nc][ks],
                                                                acc[mr][nc], 0, 0, 0);
  }

  if (ntile == 0) {
    unsigned short* dst = (wid & 1) ? k : q;
#pragma unroll
    for (int mr = 0; mr < 4; ++mr)
#pragma unroll
      for (int nc = 0; nc < 4; ++nc)
#pragma unroll
        for (int r = 0; r < 4; ++r) {
          int grow = rbase + wr + mr * 16 + l4 * 4 + r;
          int col = nc * 16 + l15;
          dst[(size_t)grow * 64 + col] = f2bf(acc[mr][nc][r]);
        }
  } else {
#pragma unroll
    for (int mr = 0; mr < 4; ++mr)
#pragma unroll
      for (int nc = 0; nc < 4; ++nc) {
        int col = ntile * 128 + wc + nc * 16 + l15 - 128;   // 0..511
        int grow = rbase + wr + mr * 16 + l4 * 4;
        int b = grow >> 12, m = grow & 4095;
        ushort4v pk;
#pragma unroll
        for (int r = 0; r < 4; ++r) pk[r] = f2bf(acc[mr][nc][r]);
        *(ushort4v*)(vT + ((size_t)b * 512 + col) * 4096 + m) = pk;
      }
  }
}

// ---------------------------------------------------------------------------
// Kernel 2 (v16, FINAL): fused sigmoid-attention = v12's proven schedule with
// FRAGMENT-MAJOR LDS layouts (conflict-reduced by construction).
// Layouts: Ps[buf][qfrag 0..7][mseg 0..7][l15][8], Vs[buf][colfrag 0..15]
// [mseg 0..7][l15][8] -> every PV wave read = 1KB contiguous (b128 floor);
// P b64 writes at 4/bank floor; V staging writes at 8/bank floor.
// Grid (32 rt, 2 ct, 4 b) = 256 blocks x 512 threads (8 waves), 1 block/CU.
// Chunk loop: loads(it+1)@top -> S(it) [K,Q regs] -> sigmoid -> Pwrite ->
// BARRIER -> PV(it) [m-split pair tiling] -> Vwrite(it+1).
// Epilogue: LDS pair-reduction (ms=1 -> ms=0), aliases Vs (64KB exact).
// LDS 96 KB. Measured R17/R19: attn ~117 us, total ~142 us, absmax 0.5.
// Structural floor of the lockstep family: 13 structural experiments
// (barriers, conflicts, occupancy, LDS traffic, V-in-reg, P-pipeline) all
// within +-5% or worse; deep-pipeline templates failed race-certification.
// ---------------------------------------------------------------------------
__global__ __launch_bounds__(512, 1) void attn_fused(
    const float* __restrict__ x, const unsigned short* __restrict__ q,
    const unsigned short* __restrict__ k, const unsigned short* __restrict__ vT,
    const float* __restrict__ gamma, float* __restrict__ out) {
  __shared__ unsigned short Vs[2][16][8][16][8];   // 64 KB [buf][cf][s][l15][e]
  __shared__ unsigned short Ps[2][8][8][16][8];    // 32 KB [buf][f][s][l15][e]
  const int tid = threadIdx.x, w = tid >> 6, lane = tid & 63;
  const int l15 = lane & 15, l4 = lane >> 4;
  const int rhalf = w >> 2;      // S: q-row half
  const int mt = w & 3;          // S: m-tile
  const int pvt = w >> 1;        // PV: col-group (0..3)
  const int ms = w & 1;          // PV: m-half (0..1)
  const int rt = blockIdx.x, ct = blockIdx.y, b = blockIdx.z;
  const int rbase = rt * 128, cbase = ct * 256;
  const unsigned short* qb = q + (size_t)b * 4096 * 64;
  const unsigned short* kp = k + (size_t)b * 4096 * 64;
  const unsigned short* vb = vT + (size_t)b * 512 * 4096;
  const float gv = gamma[0];
  const int vst_c = tid >> 1, vhalf = tid & 1;   // V staging: 64 B/thread

  // q fragments, register-resident
  bf16x8 qf[4][2];
#pragma unroll
  for (int rf = 0; rf < 4; ++rf)
#pragma unroll
    for (int ks = 0; ks < 2; ++ks)
      qf[rf][ks] = *(const bf16x8*)(qb +
          (size_t)(rbase + rhalf * 64 + rf * 16 + l15) * 64 + ks * 32 + l4 * 8);

  // ---- prologue: K(0) frags to regs; stage V(0) into Vs[0] ----
  bf16x8 kfc[2];
#pragma unroll
  for (int ks = 0; ks < 2; ++ks)
    kfc[ks] = *(const bf16x8*)(kp + (size_t)(mt * 16 + l15) * 64 + ks * 32 + l4 * 8);
  {
    bf16x8 vv[4];
#pragma unroll
    for (int i = 0; i < 4; ++i)
      vv[i] = *(const bf16x8*)(vb + (size_t)(cbase + vst_c) * 4096 + vhalf * 32 + i * 8);
#pragma unroll
    for (int i = 0; i < 4; ++i)
      *(bf16x8*)&Vs[0][vst_c >> 4][vhalf * 4 + i][vst_c & 15][0] = vv[i];
  }

  f32x4 oacc[8][4] = {};   // 128 rows x 64 cols partial (m-half ms)

  for (int it = 0; it < 64; ++it) {
    const int mb_n = (it + 1) * 64;
    const bool pf = (it < 63);
    const int p = it & 1;
    bf16x8 kfn[2], vv[4];
    if (pf) {   // issue next chunk's loads; consumed a full chunk later
#pragma unroll
      for (int ks = 0; ks < 2; ++ks)
        kfn[ks] = *(const bf16x8*)(kp + (size_t)(mb_n + mt * 16 + l15) * 64 + ks * 32 + l4 * 8);
#pragma unroll
      for (int i = 0; i < 4; ++i)
        vv[i] = *(const bf16x8*)(vb + (size_t)(cbase + vst_c) * 4096 + mb_n + vhalf * 32 + i * 8);
    }

    // ---- S^T = K.Q^T : wave (rhalf,mt): m-tile mt (16 m) x 64 q-rows ----
    f32x4 sacc[4] = {};
#pragma unroll
    for (int ks = 0; ks < 2; ++ks)
#pragma unroll
      for (int rf = 0; rf < 4; ++rf)
        sacc[rf] = __builtin_amdgcn_mfma_f32_16x16x32_bf16(kfc[ks], qf[rf][ks], sacc[rf], 0, 0, 0);

    // ---- sigmoid (q pre-scaled by log2e) + pack -> b64 P write ----
#pragma unroll
    for (int rf = 0; rf < 4; ++rf) {
      ushort4v pk;
#pragma unroll
      for (int r = 0; r < 4; ++r) {
        float s = sacc[rf][r];
        pk[r] = f2bf(__builtin_amdgcn_rcpf(1.0f + __builtin_amdgcn_exp2f(-s)));
      }
      *(ushort4v*)&Ps[p][rhalf * 4 + rf][mt * 2 + (l4 >> 1)][l15][(l4 & 1) * 4] = pk;
    }
    __syncthreads();   // the ONLY barrier per chunk

    // ---- PV(it): tile 128 rows x 64 cols (pvt), m-slice ms*32..+32 ----
    __builtin_amdgcn_s_setprio(1);
    {
      bf16x8 af[8], bfr[4];
#pragma unroll
      for (int mr = 0; mr < 8; ++mr)
        af[mr] = *(const bf16x8*)&Ps[p][mr][ms * 4 + l4][l15][0];
#pragma unroll
      for (int nc = 0; nc < 4; ++nc)
        bfr[nc] = *(const bf16x8*)&Vs[p][pvt * 4 + nc][ms * 4 + l4][l15][0];
#pragma unroll
      for (int mr = 0; mr < 8; ++mr)
#pragma unroll
        for (int nc = 0; nc < 4; ++nc)
          oacc[mr][nc] = __builtin_amdgcn_mfma_f32_16x16x32_bf16(af[mr], bfr[nc],
                                                                 oacc[mr][nc], 0, 0, 0);
    }
    __builtin_amdgcn_s_setprio(0);

    // ---- write prefetched V(it+1) into other buffer; rotate K frags ----
    if (pf) {
#pragma unroll
      for (int i = 0; i < 4; ++i)
        *(bf16x8*)&Vs[p ^ 1][vst_c >> 4][vhalf * 4 + i][vst_c & 15][0] = vv[i];
      kfc[0] = kfn[0]; kfc[1] = kfn[1];
    }
  }

  // ---- epilogue: pair-reduce (ms=1 -> ms=0) via LDS, then gamma*O + x ----
  float* red = (float*)&Vs[0][0][0][0][0];   // 4 tiles x 64 rows x 64 cols f32 = 64 KB
  __syncthreads();   // chunk loop done; safe to reuse Vs
#pragma unroll
  for (int h = 0; h < 2; ++h) {
    if (ms == 1) {
#pragma unroll
      for (int m4 = 0; m4 < 4; ++m4)
#pragma unroll
        for (int nc = 0; nc < 4; ++nc)
#pragma unroll
          for (int r = 0; r < 4; ++r)
            red[(pvt * 64 + m4 * 16 + l4 * 4 + r) * 64 + nc * 16 + l15] =
                oacc[h * 4 + m4][nc][r];
    }
    __syncthreads();
    if (ms == 0) {
#pragma unroll
      for (int m4 = 0; m4 < 4; ++m4)
#pragma unroll
        for (int nc = 0; nc < 4; ++nc)
#pragma unroll
          for (int r = 0; r < 4; ++r) {
            int mr = h * 4 + m4;
            float sum = oacc[mr][nc][r] +
                red[(pvt * 64 + m4 * 16 + l4 * 4 + r) * 64 + nc * 16 + l15];
            int grow = rbase + mr * 16 + l4 * 4 + r;
            int col = cbase + pvt * 64 + nc * 16 + l15;
            size_t idx = ((size_t)b * 4096 + grow) * 512 + col;
            out[idx] = gv * sum + x[idx];
          }
    }
    __syncthreads();
  }
}

extern "C" void kernel_launch(void* const* d_in, const int* in_sizes, int n_in,
                              void* d_out, int out_size, void* d_ws, size_t ws_size,
                              hipStream_t stream) {
  const float* x     = (const float*)d_in[0];
  const float* Wq    = (const float*)d_in[1];
  const float* Wk    = (const float*)d_in[2];
  const float* Wv    = (const float*)d_in[3];
  const float* gamma = (const float*)d_in[4];
  float* out = (float*)d_out;

  char* ws = (char*)d_ws;
  unsigned short* qbuf = (unsigned short*)(ws);                       // 2 MB
  unsigned short* kbuf = (unsigned short*)(ws + (2ull << 20));        // 2 MB
  unsigned short* vT   = (unsigned short*)(ws + (4ull << 20));        // 16 MB
  unsigned short* WbT  = (unsigned short*)(ws + (20ull << 20));       // 640 KB

  hipLaunchKernelGGL(wt_prep, dim3(1280), dim3(256), 0, stream, Wq, Wk, Wv, WbT);
  hipLaunchKernelGGL(proj_gemm, dim3(128, 5), dim3(256), 0, stream, x, WbT, qbuf, kbuf, vT);
  hipLaunchKernelGGL(attn_fused, dim3(32, 2, 4), dim3(512), 0, stream,
                     x, qbuf, kbuf, vT, gamma, out);
}